// Round 3
// baseline (465.149 us; speedup 1.0000x reference)
//
#include <hip/hip_runtime.h>
#include <hip/hip_bf16.h>

#define NN 100000
#define DD 64
#define EE 400000
#define TT 5

#define SCAN_TOTAL 500000        /* T*N bins */
#define SCAN_T 256
#define SCAN_PER 1024            /* bins per scan block (2^10: boff index = bin>>10) */
#define SCAN_B 512               /* 512*1024 >= 500000 */

typedef __bf16 bf16x8 __attribute__((ext_vector_type(8)));
typedef float  f32x4  __attribute__((ext_vector_type(4)));

// ws layout (bytes) — total 40,914,240 envelope (unchanged tail offsets)
#define OFF_XBF  0u            // N*D ushort      = 12,800,000
#define OFF_WT   12800000u     // T*64*128 ushort = 81,920
#define OFF_CTOT 12881920u     // T*N u32 (cnt_tot) = 2,000,000
#define OFF_WGT  14881920u     // T f32 (pad 64)
#define OFF_CUR  14881984u     // T*N u32 (scan of totals; consumed as mutable
                               //          position counters by k_fill) = 2,000,000
#define OFF_BS   16881984u     // 512 u32 (pad 2048)
#define OFF_BO   16884032u     // 512 u32 (pad 2048)
#define OFF_DST  24914240u     // 2M int (sorted dst) = 8,000,000
#define OFF_SEG  32914240u     // 2M int (seg src)    = 8,000,000 -> 40,914,240

__device__ __forceinline__ unsigned short f2bf(float f) {
    union { float f; unsigned u; } v; v.f = f;
    unsigned u = v.u;
    return (unsigned short)((u + 0x7FFFu + ((u >> 16) & 1u)) >> 16);  // RNE
}

// ---------------- Phase 1: init / convert / out-zero / cnt_tot-zero ----------
__global__ void k_init(const float* __restrict__ x, const float* __restrict__ W,
                       const float* __restrict__ ea,
                       unsigned short* __restrict__ xbf, unsigned short* __restrict__ wT,
                       float* __restrict__ wgt, float* __restrict__ out,
                       unsigned* __restrict__ cnt_tot) {
    int i = blockIdx.x * blockDim.x + threadIdx.x;   // grid covers N*D exactly
    if (i < NN * DD) {
        out[i] = 0.0f;
        xbf[i] = f2bf(x[i]);
    }
    if (i < SCAN_TOTAL) cnt_tot[i] = 0u;             // histogram target
    if (i < TT * 128 * 64) {
        int t = i >> 13;          // /8192
        int rem = i & 8191;
        int d = rem >> 7;         // /128
        int k = rem & 127;
        wT[i] = f2bf(W[t * 8192 + k * 64 + d]);   // wT[t][d][k] = W[t][k][d]
    }
    if (i == 0) {
        float m = -1e30f;
        for (int t = 0; t < TT; t++) m = fmaxf(m, ea[t]);
        float e[TT]; float s = 0.0f;
        for (int t = 0; t < TT; t++) { e[t] = __expf(ea[t] - m); s += e[t]; }
        for (int t = 0; t < TT; t++) wgt[t] = e[t] / s;
    }
}

// ---------------- Phase 2a: global-atomic histogram. 2M device atomics on
// 500k bins (avg 4/bin) — k_edge proves the fabric does >=174 G atomic/s,
// so this is ~10 us at FULL grid width (vs 80-block LDS crawl). ---------------
__global__ __launch_bounds__(256) void k_hist(const int* __restrict__ edges,
                                              unsigned* __restrict__ cnt_tot) {
    const int t = blockIdx.y;
    const int i = blockIdx.x * 256 + threadIdx.x;
    if (i >= EE / 4) return;
    int4 v = reinterpret_cast<const int4*>(edges + (size_t)t * 2 * EE)[i];
    unsigned* c = cnt_tot + t * NN;
    atomicAdd(&c[v.x], 1u);
    atomicAdd(&c[v.y], 1u);
    atomicAdd(&c[v.z], 1u);
    atomicAdd(&c[v.w], 1u);
}

// ---------------- Phase 2b: exclusive scan over T*N bins ---------------------
__global__ void k_scan1(const unsigned* __restrict__ cnt_tot,
                        unsigned* __restrict__ cur, unsigned* __restrict__ bsum) {
    __shared__ unsigned s[SCAN_T];
    const int b = blockIdx.x, tid = threadIdx.x;
    const int base = b * SCAN_PER + tid * 4;   // bin index (500000 % 4 == 0)
    unsigned tot[4] = {0u, 0u, 0u, 0u};
    if (base < SCAN_TOTAL) {
        uint4 tv = *reinterpret_cast<const uint4*>(cnt_tot + base);
        tot[0] = tv.x; tot[1] = tv.y; tot[2] = tv.z; tot[3] = tv.w;
    }
    const unsigned tsum = tot[0] + tot[1] + tot[2] + tot[3];
    s[tid] = tsum;
    __syncthreads();
    unsigned inc = tsum;
    for (int d = 1; d < SCAN_T; d <<= 1) {
        unsigned add = (tid >= d) ? s[tid - d] : 0u;
        __syncthreads();
        inc += add;
        s[tid] = inc;
        __syncthreads();
    }
    if (tid == SCAN_T - 1) bsum[b] = inc;
    const unsigned p0 = inc - tsum;
    if (base < SCAN_TOTAL) {
        *reinterpret_cast<uint4*>(cur + base) =
            make_uint4(p0, p0 + tot[0], p0 + tot[0] + tot[1], p0 + tot[0] + tot[1] + tot[2]);
    }
}

__global__ void k_scan2(const unsigned* __restrict__ bsum, unsigned* __restrict__ boff) {
    __shared__ unsigned s[SCAN_B];
    const int tid = threadIdx.x;
    const unsigned v = bsum[tid];
    s[tid] = v;
    __syncthreads();
    unsigned inc = v;
    for (int d = 1; d < SCAN_B; d <<= 1) {
        unsigned add = (tid >= d) ? s[tid - d] : 0u;
        __syncthreads();
        inc += add;
        s[tid] = inc;
        __syncthreads();
    }
    boff[tid] = inc - v;
}

// ---------------- Phase 2c: direct global-atomic counting-sort fill.
// cur[bin] (scan1's local prefix) IS the mutable rank counter; absolute slot =
// atomicAdd(&cur[bin],1) + boff[bin>>10]. Writes sdst AND seg in one pass —
// replaces k_pscat + k_bfill + k_seg. Order within a (t,src) segment is
// arbitrary (sum is order-independent; k_edge only needs grouping). ----------
__global__ __launch_bounds__(256) void k_fill(const int* __restrict__ edges,
                                              unsigned* __restrict__ cur,
                                              const unsigned* __restrict__ boff,
                                              int* __restrict__ sdst,
                                              int* __restrict__ seg) {
    const int t = blockIdx.y;
    const int i = blockIdx.x * 256 + threadIdx.x;
    if (i >= EE / 4) return;
    const int* srcp = edges + (size_t)t * 2 * EE;
    const int* dstp = srcp + EE;
    int4 v = reinterpret_cast<const int4*>(srcp)[i];
    int4 w = reinterpret_cast<const int4*>(dstp)[i];
    const int base = t * NN;
    {
        int bin = base + v.x;
        unsigned p = atomicAdd(&cur[bin], 1u) + boff[bin >> 10];
        sdst[p] = w.x; seg[p] = v.x;
    }
    {
        int bin = base + v.y;
        unsigned p = atomicAdd(&cur[bin], 1u) + boff[bin >> 10];
        sdst[p] = w.y; seg[p] = v.y;
    }
    {
        int bin = base + v.z;
        unsigned p = atomicAdd(&cur[bin], 1u) + boff[bin >> 10];
        sdst[p] = w.z; seg[p] = v.z;
    }
    {
        int bin = base + v.w;
        unsigned p = atomicAdd(&cur[bin], 1u) + boff[bin >> 10];
        sdst[p] = w.w; seg[p] = v.w;
    }
}

// ---------------- Phase 3: gather -> MFMA -> wave-cooperative segmented scatter.
// EXACT round-0 kernel (proven 184 us, reproduced in R2). ---------------------
__global__ __launch_bounds__(256) void k_edge(
    const unsigned short* __restrict__ xbf, const unsigned short* __restrict__ wT,
    const float* __restrict__ b, const int* __restrict__ sdst,
    const int* __restrict__ seg, const unsigned* __restrict__ cnt,
    const float* __restrict__ wgt, float* __restrict__ out) {
    const int t  = blockIdx.y;
    const int e0 = blockIdx.x * 128;

    __shared__ __align__(16) unsigned short Ab[128][136];   // feats tile; reused as f32 proj[128][68]
    __shared__ float scale_s[128];
    __shared__ int   src_s[132];                             // padded

    const int tid = threadIdx.x;

    // stage A: gather x rows (bf16, 128B each); thread pair per sorted edge
    {
        int e = tid >> 1, half = tid & 1;
        size_t pos = (size_t)t * EE + e0 + e;
        int idx = half ? sdst[pos] : seg[pos];
        const float4* g = reinterpret_cast<const float4*>(xbf + (size_t)idx * 64);
        float4* l = reinterpret_cast<float4*>(&Ab[e][half * 64]);
#pragma unroll
        for (int c = 0; c < 8; c++) l[c] = g[c];
        if (half == 0) {
            src_s[e] = idx;
            scale_s[e] = wgt[t] / (float)cnt[t * NN + idx];   // cnt_tot table is L2-hot
        }
    }
    __syncthreads();

    const int wv = tid >> 6, lane = tid & 63;
    const int m16 = lane & 15, quad = lane >> 4;
    const unsigned short* wrow = wT + (size_t)t * 8192;      // [d][k], 64x128

    f32x4 acc[2][4];
#pragma unroll
    for (int tm = 0; tm < 2; tm++)
#pragma unroll
        for (int tn = 0; tn < 4; tn++)
            acc[tm][tn] = (f32x4){0.f, 0.f, 0.f, 0.f};

#pragma unroll
    for (int kk = 0; kk < 128; kk += 32) {
        const int kb = kk + quad * 8;
        bf16x8 af[2], bfr[4];
#pragma unroll
        for (int tm = 0; tm < 2; tm++)
            af[tm] = *reinterpret_cast<const bf16x8*>(&Ab[wv * 32 + tm * 16 + m16][kb]);
#pragma unroll
        for (int tn = 0; tn < 4; tn++)
            bfr[tn] = *reinterpret_cast<const bf16x8*>(wrow + (tn * 16 + m16) * 128 + kb);
#pragma unroll
        for (int tm = 0; tm < 2; tm++)
#pragma unroll
            for (int tn = 0; tn < 4; tn++)
                acc[tm][tn] = __builtin_amdgcn_mfma_f32_16x16x32_bf16(
                    af[tm], bfr[tn], acc[tm][tn], 0, 0, 0);
    }

    // all waves done reading Ab before we overwrite it with f32 proj
    __syncthreads();

    float bias[4];
#pragma unroll
    for (int tn = 0; tn < 4; tn++) bias[tn] = b[t * 64 + tn * 16 + m16];

    float* proj = reinterpret_cast<float*>(&Ab[0][0]);   // [128][68] f32, stride 68
#pragma unroll
    for (int tm = 0; tm < 2; tm++) {
#pragma unroll
        for (int r = 0; r < 4; r++) {
            const int eloc = wv * 32 + tm * 16 + quad * 4 + r;   // in [wv*32, wv*32+32)
            const float s = scale_s[eloc];
#pragma unroll
            for (int tn = 0; tn < 4; tn++) {
                float v = acc[tm][tn][r] + bias[tn];
                v = v > 0.f ? v : 0.f;
                proj[eloc * 68 + tn * 16 + m16] = v * s;
            }
        }
    }
    // NO barrier: wave wv wrote exactly proj rows [wv*32, wv*32+32) and reads
    // only those below. (src_s/scale_s were synced by the earlier barrier.)

    // wave-cooperative segmented reduce: lane = feature, walk 32 sorted edges,
    // flush one COALESCED 256B atomic burst per segment.
    {
        const int j0 = wv * 32;
        float sum = 0.f;
#pragma unroll
        for (int j = j0; j < j0 + 32; j++) {
            sum += proj[j * 68 + lane];
            const bool flush = (j == j0 + 31) || (src_s[j + 1] != src_s[j]);
            if (flush) {
                atomicAdd(out + (size_t)src_s[j] * 64 + lane, sum);
                sum = 0.f;
            }
        }
    }
}

extern "C" void kernel_launch(void* const* d_in, const int* in_sizes, int n_in,
                              void* d_out, int out_size, void* d_ws, size_t ws_size,
                              hipStream_t stream) {
    const float* x     = (const float*)d_in[0];
    const float* W     = (const float*)d_in[1];
    const float* b     = (const float*)d_in[2];
    const float* ea    = (const float*)d_in[3];
    const int*   edges = (const int*)d_in[4];
    float* out = (float*)d_out;

    char* ws = (char*)d_ws;
    unsigned short* xbf  = (unsigned short*)(ws + OFF_XBF);
    unsigned short* wT   = (unsigned short*)(ws + OFF_WT);
    unsigned* cnt_tot    = (unsigned*)(ws + OFF_CTOT);
    float* wgt           = (float*)(ws + OFF_WGT);
    unsigned* cur        = (unsigned*)(ws + OFF_CUR);
    unsigned* bsum       = (unsigned*)(ws + OFF_BS);
    unsigned* boff       = (unsigned*)(ws + OFF_BO);
    int* sdst            = (int*)(ws + OFF_DST);
    int* seg             = (int*)(ws + OFF_SEG);

    const int EB = (EE / 4 + 255) / 256;   // 391 blocks per t

    // Phase 1: out-zero, cnt-zero, x->bf16, W^T, softmax
    k_init<<<(NN * DD) / 256, 256, 0, stream>>>(x, W, ea, xbf, wT, wgt, out, cnt_tot);

    // Phase 2: global-atomic histogram -> scan -> direct counting-sort fill
    k_hist<<<dim3(EB, TT), 256, 0, stream>>>(edges, cnt_tot);
    k_scan1<<<SCAN_B, SCAN_T, 0, stream>>>(cnt_tot, cur, bsum);
    k_scan2<<<1, SCAN_B, 0, stream>>>(bsum, boff);
    k_fill<<<dim3(EB, TT), 256, 0, stream>>>(edges, cur, boff, sdst, seg);

    // Phase 3: MFMA gather-GEMM + wave-cooperative segmented scatter
    dim3 grid(EE / 128, TT);
    k_edge<<<grid, 256, 0, stream>>>(xbf, wT, b, sdst, seg, cnt_tot, wgt, out);
}